// Round 1
// 185.058 us; speedup vs baseline: 1.0171x; 1.0171x over previous
//
#include <hip/hip_runtime.h>
#include <hip/hip_bf16.h>

#define BATCH 2
#define SEQL 2048
#define NH 16
#define DH 64
#define DM 1024
#define LDK 72   // P-tile LDS row stride (bf16): 144B rows -> 2-way (free) reads
// Q pre-scale folded into qkv_gemm epilogue: 1/sqrt(64) * log2(e)
#define QSCALE 0.1803368801111244f

typedef __hip_bfloat16 bf16;
typedef __attribute__((ext_vector_type(8))) short  bf16x8;
typedef __attribute__((ext_vector_type(4))) float  f32x4;

__device__ __forceinline__ void gl_lds16(const void* g, void* l) {
    __builtin_amdgcn_global_load_lds(
        (const __attribute__((address_space(1))) unsigned int*)g,
        (__attribute__((address_space(3))) unsigned int*)l, 16, 0, 0);
}

// ---------------------------------------------------------------------------
// Prep (fused): z<4 -> weight transpose to bf16 Bt[n][k]; z==4 -> x fp32->bf16
// (grid-stride). grid (16,16,5), block 256.
// ---------------------------------------------------------------------------
__global__ __launch_bounds__(256) void prep_kernel(
    const float* __restrict__ x,
    const float* __restrict__ Wq, const float* __restrict__ Wk,
    const float* __restrict__ Wv, const float* __restrict__ Wo,
    bf16* __restrict__ Wt, bf16* __restrict__ xb)
{
    const int zi = blockIdx.z;
    if (zi == 4) {
        // xconv: 256 blocks x 256 thr x 4 elems x 16 iters = 4M elems
        const int bid = blockIdx.y * 16 + blockIdx.x;
        const size_t base = ((size_t)bid * 256 + threadIdx.x) * 4;
        #pragma unroll
        for (int it = 0; it < 16; ++it) {
            const size_t i = base + (size_t)it * 262144;
            const float4 v = *(const float4*)(x + i);
            bf16 o[4];
            o[0] = __float2bfloat16(v.x); o[1] = __float2bfloat16(v.y);
            o[2] = __float2bfloat16(v.z); o[3] = __float2bfloat16(v.w);
            *(uint2*)(xb + i) = *(const uint2*)o;
        }
        return;
    }

    __shared__ float ts[64][65];
    const float* src = (zi == 0) ? Wq : (zi == 1) ? Wk : (zi == 2) ? Wv : Wo;
    bf16* dst = Wt + (size_t)zi * DM * DM;
    const int row0 = blockIdx.y * 64;
    const int col0 = blockIdx.x * 64;
    const int tx = threadIdx.x & 63;
    const int ty = threadIdx.x >> 6;

    if (zi < 3) {
        const int h = col0 >> 6;
        #pragma unroll
        for (int i = 0; i < 16; ++i) {
            const int r = ty + 4 * i;
            ts[r][tx] = src[h * (DM * DH) + (row0 + r) * DH + tx];
        }
    } else {
        #pragma unroll
        for (int i = 0; i < 16; ++i) {
            const int r = ty + 4 * i;
            ts[r][tx] = src[(size_t)(row0 + r) * DM + col0 + tx];
        }
    }
    __syncthreads();
    #pragma unroll
    for (int i = 0; i < 16; ++i) {
        const int rr = ty + 4 * i;
        dst[(size_t)(col0 + rr) * DM + row0 + tx] = __float2bfloat16(ts[tx][rr]);
    }
}

// ---------------------------------------------------------------------------
// QKV GEMM v3 (round-10 config): 2 K-steps per barrier, round-6 epilogue.
// grid (8, 32, 3), block 256.
// ---------------------------------------------------------------------------
__global__ __launch_bounds__(256) void qkv_gemm(
    const bf16* __restrict__ xb, const bf16* __restrict__ Wt,
    const float* __restrict__ bq, const float* __restrict__ bk, const float* __restrict__ bv,
    bf16* __restrict__ qkv)
{
    __shared__ __align__(16) bf16 As[2][128 * 32];
    __shared__ __align__(16) bf16 Bs[2][128 * 32];

    const int t = threadIdx.x;
    const int lane = t & 63, w = t >> 6;
    const int ml = lane & 15, quad = lane >> 4;
    const int wr = w >> 1, wc = w & 1;
    const int bn = blockIdx.x, bm = blockIdx.y, which = blockIdx.z;

    const bf16* A0 = xb + (size_t)(bm * 128) * DM;
    const bf16* B0 = Wt + (size_t)which * DM * DM + (size_t)(bn * 128) * DM;
    const float* bias = (which == 0) ? bq : (which == 1) ? bk : bv;
    bf16* outb = qkv + (size_t)which * (BATCH * SEQL * NH * DH);
    const float oscale = (which == 0) ? QSCALE : 1.0f;

    f32x4 acc[4][4];
    #pragma unroll
    for (int i = 0; i < 4; ++i)
        #pragma unroll
        for (int j = 0; j < 4; ++j) acc[i][j] = (f32x4){0.f, 0.f, 0.f, 0.f};

    const int r0 = t >> 2, c0 = (t & 3) * 8;
    const int f1 = t + 256;
    const int r1 = f1 >> 2, c1 = (f1 & 3) * 8;

    for (int kt = 0; kt < DM / 64; ++kt) {
        const int k0 = kt * 64;
        __syncthreads();
        #pragma unroll
        for (int half = 0; half < 2; ++half) {
            const int kh = k0 + half * 32;
            gl_lds16(A0 + (size_t)r0 * DM + kh + c0, &As[half][t * 8]);
            gl_lds16(A0 + (size_t)r1 * DM + kh + c1, &As[half][f1 * 8]);
            gl_lds16(B0 + (size_t)r0 * DM + kh + c0, &Bs[half][t * 8]);
            gl_lds16(B0 + (size_t)r1 * DM + kh + c1, &Bs[half][f1 * 8]);
        }
        __syncthreads();
        #pragma unroll
        for (int half = 0; half < 2; ++half) {
            bf16x8 af[4], bfr[4];
            #pragma unroll
            for (int i = 0; i < 4; ++i)
                af[i] = *(const bf16x8*)&As[half][(wr * 64 + i * 16 + ml) * 32 + quad * 8];
            #pragma unroll
            for (int j = 0; j < 4; ++j)
                bfr[j] = *(const bf16x8*)&Bs[half][(wc * 64 + j * 16 + ml) * 32 + quad * 8];
            #pragma unroll
            for (int i = 0; i < 4; ++i)
                #pragma unroll
                for (int j = 0; j < 4; ++j)
                    acc[i][j] = __builtin_amdgcn_mfma_f32_16x16x32_bf16(af[i], bfr[j], acc[i][j], 0, 0, 0);
        }
    }

    float bb[4];
    #pragma unroll
    for (int j = 0; j < 4; ++j) bb[j] = bias[bn * 128 + wc * 64 + j * 16 + ml];

    if (which == 2) {
        #pragma unroll
        for (int i = 0; i < 4; ++i) {
            const int row0v = bm * 128 + wr * 64 + i * 16 + quad * 4;
            const int b = row0v >> 11;
            const int s0 = row0v & (SEQL - 1);
            #pragma unroll
            for (int j = 0; j < 4; ++j) {
                const int col = bn * 128 + wc * 64 + j * 16 + ml;
                const int h = col >> 6, d = col & 63;
                bf16 tmp[4];
                #pragma unroll
                for (int rg = 0; rg < 4; ++rg)
                    tmp[rg] = __float2bfloat16(acc[i][j][rg] + bb[j]);
                *(uint2*)&outb[(((size_t)(b * NH + h)) * DH + d) * SEQL + s0] =
                    *(const uint2*)tmp;
            }
        }
    } else {
        #pragma unroll
        for (int i = 0; i < 4; ++i) {
            #pragma unroll
            for (int rg = 0; rg < 4; ++rg) {
                const int row = bm * 128 + wr * 64 + i * 16 + quad * 4 + rg;
                const int b = row >> 11;
                const int s = row & (SEQL - 1);
                #pragma unroll
                for (int j = 0; j < 4; ++j) {
                    const int col = bn * 128 + wc * 64 + j * 16 + ml;
                    const int h = col >> 6, d = col & 63;
                    outb[(((size_t)(b * NH + h)) * SEQL + s) * DH + d] =
                        __float2bfloat16((acc[i][j][rg] + bb[j]) * oscale);
                }
            }
        }
    }
}

// ---------------------------------------------------------------------------
// O-proj GEMM v3: 128x64 tiles, 2 K-steps per barrier. grid (16,32), block 256.
// ---------------------------------------------------------------------------
__global__ __launch_bounds__(256) void oproj_gemm(
    const bf16* __restrict__ zb, const bf16* __restrict__ Bt,
    const float* __restrict__ bo, float* __restrict__ out)
{
    __shared__ __align__(16) bf16 As[2][128 * 32];
    __shared__ __align__(16) bf16 Bs[2][64 * 32];

    const int t = threadIdx.x;
    const int lane = t & 63, w = t >> 6;
    const int ml = lane & 15, quad = lane >> 4;
    const int wr = w >> 1, wc = w & 1;
    const int bn = blockIdx.x, bm = blockIdx.y;

    const bf16* A0 = zb + (size_t)(bm * 128) * DM;
    const bf16* B0 = Bt + (size_t)(bn * 64) * DM;

    f32x4 acc[4][2];
    #pragma unroll
    for (int i = 0; i < 4; ++i)
        #pragma unroll
        for (int j = 0; j < 2; ++j) acc[i][j] = (f32x4){0.f, 0.f, 0.f, 0.f};

    const int r0 = t >> 2, c0 = (t & 3) * 8;
    const int f1 = t + 256;
    const int r1 = f1 >> 2, c1 = (f1 & 3) * 8;

    for (int kt = 0; kt < DM / 64; ++kt) {
        const int k0 = kt * 64;
        __syncthreads();
        #pragma unroll
        for (int half = 0; half < 2; ++half) {
            const int kh = k0 + half * 32;
            gl_lds16(A0 + (size_t)r0 * DM + kh + c0, &As[half][t * 8]);
            gl_lds16(A0 + (size_t)r1 * DM + kh + c1, &As[half][f1 * 8]);
            gl_lds16(B0 + (size_t)r0 * DM + kh + c0, &Bs[half][t * 8]);
        }
        __syncthreads();
        #pragma unroll
        for (int half = 0; half < 2; ++half) {
            bf16x8 af[4], bfr[2];
            #pragma unroll
            for (int i = 0; i < 4; ++i)
                af[i] = *(const bf16x8*)&As[half][(wr * 64 + i * 16 + ml) * 32 + quad * 8];
            #pragma unroll
            for (int j = 0; j < 2; ++j)
                bfr[j] = *(const bf16x8*)&Bs[half][(wc * 32 + j * 16 + ml) * 32 + quad * 8];
            #pragma unroll
            for (int i = 0; i < 4; ++i)
                #pragma unroll
                for (int j = 0; j < 2; ++j)
                    acc[i][j] = __builtin_amdgcn_mfma_f32_16x16x32_bf16(af[i], bfr[j], acc[i][j], 0, 0, 0);
        }
    }

    float bb[2];
    #pragma unroll
    for (int j = 0; j < 2; ++j) bb[j] = bo[bn * 64 + wc * 32 + j * 16 + ml];

    #pragma unroll
    for (int i = 0; i < 4; ++i) {
        #pragma unroll
        for (int rg = 0; rg < 4; ++rg) {
            const int row = bm * 128 + wr * 64 + i * 16 + quad * 4 + rg;
            #pragma unroll
            for (int j = 0; j < 2; ++j) {
                const int col = bn * 64 + wc * 32 + j * 16 + ml;
                out[(size_t)row * DM + col] = acc[i][j][rg] + bb[j];
            }
        }
    }
}

// ---------------------------------------------------------------------------
// MFMA flash attention v7: v6 structure (64 Q rows/block, no-max softmax,
// ones-column row-sums, V^T global, XOR-swizzled K/V staging) + 2-phase
// SOFTWARE PIPELINE: K/V double-buffered in LDS; the global_load_lds for tile
// kt+1 is issued right after the top barrier, BEFORE computing tile kt, so the
// compiler's vmcnt(0)-drain-at-barrier lands after a full compute phase and
// the ~200-300cy L2 load latency hides under QK^T/softmax/PV (T3-minimum).
// MFMA clusters wrapped in s_setprio(1)/(0) (T5, attn-proven).
// grid = (bh=32, qt=32 reversed), block 256.
// ---------------------------------------------------------------------------
__global__ __launch_bounds__(256) void attn_kernel(
    const bf16* __restrict__ qg, const bf16* __restrict__ kg, const bf16* __restrict__ vtg,
    bf16* __restrict__ z)
{
    __shared__ __align__(16) bf16 KsS[2][64 * 64];   // 2 x 8192 B, swizzled
    __shared__ __align__(16) bf16 VtS[2][64 * 64];   // 2 x 8192 B, swizzled ([d][s_local])
    __shared__ bf16 PsS[4][16 * LDK];                // 9216 B (per-wave P tiles)

    const int t    = threadIdx.x;
    const int lane = t & 63;
    const int w    = t >> 6;
    const int m    = lane & 15;
    const int quad = lane >> 4;

    const int bh = blockIdx.x;
    const int b  = bh >> 4;
    const int h  = bh & 15;
    const int qt = (gridDim.y - 1) - blockIdx.y;
    const int q0 = qt * 64;

    const size_t base   = (size_t)bh * SEQL * DH;  // q/k base ([b,h,s,d])
    const size_t vtbase = (size_t)bh * DH * SEQL;  // v^T base ([b,h,d,s])

    // staging slots: wave w covers slots [w*128, w*128+128) via 2 gl_lds16 each
    const int s0 = w * 128 + lane;            // instruction 0 slot
    const int s1 = s0 + 64;                   // instruction 1 slot
    const int r0s = s0 >> 3, c0s = (s0 & 7) ^ (r0s & 7);
    const int r1s = s1 >> 3, c1s = (s1 & 7) ^ (r1s & 7);

    bf16x8 aq[2];
    {
        const bf16* qp = qg + base + (size_t)(q0 + w * 16 + m) * DH + quad * 8;
        aq[0] = *(const bf16x8*)(qp);
        aq[1] = *(const bf16x8*)(qp + 32);
    }

    const short ob = (m == 0) ? (short)0x3F80 : (short)0;
    const bf16x8 bones = {ob, ob, ob, ob, ob, ob, ob, ob};

    f32x4 zacc[4];
    #pragma unroll
    for (int nt = 0; nt < 4; ++nt) zacc[nt] = (f32x4){0.f, 0.f, 0.f, 0.f};
    f32x4 lacc = (f32x4){0.f, 0.f, 0.f, 0.f};

    bf16* Psw = PsS[w];

    // ---- prologue: stage tile 0 into buffer 0 ----
    {
        gl_lds16(kg + base + (size_t)r0s * DH + c0s * 8, &KsS[0][s0 * 8]);
        gl_lds16(kg + base + (size_t)r1s * DH + c1s * 8, &KsS[0][s1 * 8]);
        gl_lds16(vtg + vtbase + (size_t)r0s * SEQL + c0s * 8, &VtS[0][s0 * 8]);
        gl_lds16(vtg + vtbase + (size_t)r1s * SEQL + c1s * 8, &VtS[0][s1 * 8]);
    }

    for (int kt = 0; kt <= qt; ++kt) {
        const int cur = kt & 1;
        // drains this wave's in-flight gl_lds (tile kt) via the compiler's
        // vmcnt(0)-before-s_barrier, and publishes the LDS writes to the block
        __syncthreads();

        // ---- issue next tile's loads into the other buffer (overlap w/ compute)
        if (kt < qt) {
            const int kc = (kt + 1) * 64;
            bf16* Kd = &KsS[cur ^ 1][0];
            bf16* Vd = &VtS[cur ^ 1][0];
            gl_lds16(kg + base + (size_t)(kc + r0s) * DH + c0s * 8, Kd + s0 * 8);
            gl_lds16(kg + base + (size_t)(kc + r1s) * DH + c1s * 8, Kd + s1 * 8);
            gl_lds16(vtg + vtbase + (size_t)r0s * SEQL + kc + c0s * 8, Vd + s0 * 8);
            gl_lds16(vtg + vtbase + (size_t)r1s * SEQL + kc + c1s * 8, Vd + s1 * 8);
        }

        const bf16* Ks = &KsS[cur][0];
        const bf16* Vt = &VtS[cur][0];

        // ---- S = Q K^T (16x64 per wave) ----
        f32x4 sc[4];
        #pragma unroll
        for (int nt = 0; nt < 4; ++nt) sc[nt] = (f32x4){0.f, 0.f, 0.f, 0.f};
        __builtin_amdgcn_s_setprio(1);
        #pragma unroll
        for (int ks = 0; ks < 2; ++ks) {
            #pragma unroll
            for (int nt = 0; nt < 4; ++nt) {
                const int row = nt * 16 + m;
                const int pc  = ((ks << 2) + quad) ^ (m & 7);
                const bf16x8 bk = *(const bf16x8*)(&Ks[row * 64 + pc * 8]);
                sc[nt] = __builtin_amdgcn_mfma_f32_16x16x32_bf16(aq[ks], bk, sc[nt], 0, 0, 0);
            }
        }
        __builtin_amdgcn_s_setprio(0);
        if (kt == qt) {
            #pragma unroll
            for (int nt = 0; nt < 4; ++nt) {
                const int col = nt * 16 + m;
                #pragma unroll
                for (int rg = 0; rg < 4; ++rg) {
                    const int row = w * 16 + quad * 4 + rg;
                    if (col > row) sc[nt][rg] = -1e30f;
                }
            }
        }

        // ---- p = 2^s (no max; offset cancels in z = sum(pv)/sum(p)) ----
        #pragma unroll
        for (int nt = 0; nt < 4; ++nt)
            #pragma unroll
            for (int rg = 0; rg < 4; ++rg)
                Psw[(quad * 4 + rg) * LDK + nt * 16 + m] =
                    __float2bfloat16(__builtin_exp2f(sc[nt][rg]));

        // ---- Z += P V, l += P * ones ----
        __builtin_amdgcn_s_setprio(1);
        #pragma unroll
        for (int ks = 0; ks < 2; ++ks) {
            const bf16x8 ap = *(const bf16x8*)(&Psw[m * LDK + ks * 32 + quad * 8]);
            lacc = __builtin_amdgcn_mfma_f32_16x16x32_bf16(ap, bones, lacc, 0, 0, 0);
            #pragma unroll
            for (int nt = 0; nt < 4; ++nt) {
                const int row = nt * 16 + m;
                const int pc  = ((ks << 2) + quad) ^ (m & 7);
                const bf16x8 bv = *(const bf16x8*)(&Vt[row * 64 + pc * 8]);
                zacc[nt] = __builtin_amdgcn_mfma_f32_16x16x32_bf16(ap, bv, zacc[nt], 0, 0, 0);
            }
        }
        __builtin_amdgcn_s_setprio(0);
    }

    float invl[4];
    #pragma unroll
    for (int rg = 0; rg < 4; ++rg)
        invl[rg] = 1.f / __shfl(lacc[rg], quad * 16);
    #pragma unroll
    for (int nt = 0; nt < 4; ++nt) {
        const int d = nt * 16 + m;
        #pragma unroll
        for (int rg = 0; rg < 4; ++rg) {
            const int qrow = q0 + w * 16 + quad * 4 + rg;
            z[(((size_t)b * SEQL + qrow) * NH + h) * DH + d] =
                __float2bfloat16(zacc[nt][rg] * invl[rg]);
        }
    }
}

// ---------------------------------------------------------------------------
extern "C" void kernel_launch(void* const* d_in, const int* in_sizes, int n_in,
                              void* d_out, int out_size, void* d_ws, size_t ws_size,
                              hipStream_t stream)
{
    const float* x  = (const float*)d_in[0];
    const float* Wq = (const float*)d_in[1];
    const float* Wk = (const float*)d_in[2];
    const float* Wv = (const float*)d_in[3];
    const float* Wo = (const float*)d_in[4];
    const float* bq = (const float*)d_in[5];
    const float* bk = (const float*)d_in[6];
    const float* bv = (const float*)d_in[7];
    const float* bo = (const float*)d_in[8];
    float* out = (float*)d_out;

    const size_t TOK = (size_t)BATCH * SEQL;             // 4096
    const size_t QKV = TOK * DM;                         // 4M elems
    bf16* xb  = (bf16*)d_ws;                             // 4M
    bf16* Wt  = xb + QKV;                                // 4 x 1M
    bf16* qkv = Wt + 4 * (size_t)DM * DM;                // 3 x 4M
    bf16* zb  = qkv + 3 * QKV;                           // 4M   (48 MB total)

    prep_kernel<<<dim3(16, 16, 5), 256, 0, stream>>>(x, Wq, Wk, Wv, Wo, Wt, xb);
    qkv_gemm<<<dim3(8, 32, 3), 256, 0, stream>>>(xb, Wt, bq, bk, bv, qkv);
    attn_kernel<<<dim3(BATCH * NH, SEQL / 64), 256, 0, stream>>>(
        qkv, qkv + QKV, qkv + 2 * QKV, zb);
    oproj_gemm<<<dim3(16, 32), 256, 0, stream>>>(zb, Wt + 3 * (size_t)DM * DM, bo, out);
}

// Round 2
// 184.768 us; speedup vs baseline: 1.0187x; 1.0016x over previous
//
#include <hip/hip_runtime.h>
#include <hip/hip_bf16.h>

#define BATCH 2
#define SEQL 2048
#define NH 16
#define DH 64
#define DM 1024
#define LDK 72   // P-tile LDS row stride (bf16): 144B rows -> 2-way (free) reads
// Q pre-scale folded into qkv_gemm epilogue: 1/sqrt(64) * log2(e)
#define QSCALE 0.1803368801111244f

typedef __hip_bfloat16 bf16;
typedef __attribute__((ext_vector_type(8))) short  bf16x8;
typedef __attribute__((ext_vector_type(4))) float  f32x4;

__device__ __forceinline__ void gl_lds16(const void* g, void* l) {
    __builtin_amdgcn_global_load_lds(
        (const __attribute__((address_space(1))) unsigned int*)g,
        (__attribute__((address_space(3))) unsigned int*)l, 16, 0, 0);
}

// ---------------------------------------------------------------------------
// Prep (fused): z<4 -> weight transpose to bf16 Bt[n][k]; z==4 -> x fp32->bf16
// (grid-stride). grid (16,16,5), block 256.
// ---------------------------------------------------------------------------
__global__ __launch_bounds__(256) void prep_kernel(
    const float* __restrict__ x,
    const float* __restrict__ Wq, const float* __restrict__ Wk,
    const float* __restrict__ Wv, const float* __restrict__ Wo,
    bf16* __restrict__ Wt, bf16* __restrict__ xb)
{
    const int zi = blockIdx.z;
    if (zi == 4) {
        // xconv: 256 blocks x 256 thr x 4 elems x 16 iters = 4M elems
        const int bid = blockIdx.y * 16 + blockIdx.x;
        const size_t base = ((size_t)bid * 256 + threadIdx.x) * 4;
        #pragma unroll
        for (int it = 0; it < 16; ++it) {
            const size_t i = base + (size_t)it * 262144;
            const float4 v = *(const float4*)(x + i);
            bf16 o[4];
            o[0] = __float2bfloat16(v.x); o[1] = __float2bfloat16(v.y);
            o[2] = __float2bfloat16(v.z); o[3] = __float2bfloat16(v.w);
            *(uint2*)(xb + i) = *(const uint2*)o;
        }
        return;
    }

    __shared__ float ts[64][65];
    const float* src = (zi == 0) ? Wq : (zi == 1) ? Wk : (zi == 2) ? Wv : Wo;
    bf16* dst = Wt + (size_t)zi * DM * DM;
    const int row0 = blockIdx.y * 64;
    const int col0 = blockIdx.x * 64;
    const int tx = threadIdx.x & 63;
    const int ty = threadIdx.x >> 6;

    if (zi < 3) {
        const int h = col0 >> 6;
        #pragma unroll
        for (int i = 0; i < 16; ++i) {
            const int r = ty + 4 * i;
            ts[r][tx] = src[h * (DM * DH) + (row0 + r) * DH + tx];
        }
    } else {
        #pragma unroll
        for (int i = 0; i < 16; ++i) {
            const int r = ty + 4 * i;
            ts[r][tx] = src[(size_t)(row0 + r) * DM + col0 + tx];
        }
    }
    __syncthreads();
    #pragma unroll
    for (int i = 0; i < 16; ++i) {
        const int rr = ty + 4 * i;
        dst[(size_t)(col0 + rr) * DM + row0 + tx] = __float2bfloat16(ts[tx][rr]);
    }
}

// ---------------------------------------------------------------------------
// QKV GEMM v3 (round-10 config): 2 K-steps per barrier, round-6 epilogue.
// grid (8, 32, 3), block 256.
// ---------------------------------------------------------------------------
__global__ __launch_bounds__(256) void qkv_gemm(
    const bf16* __restrict__ xb, const bf16* __restrict__ Wt,
    const float* __restrict__ bq, const float* __restrict__ bk, const float* __restrict__ bv,
    bf16* __restrict__ qkv)
{
    __shared__ __align__(16) bf16 As[2][128 * 32];
    __shared__ __align__(16) bf16 Bs[2][128 * 32];

    const int t = threadIdx.x;
    const int lane = t & 63, w = t >> 6;
    const int ml = lane & 15, quad = lane >> 4;
    const int wr = w >> 1, wc = w & 1;
    const int bn = blockIdx.x, bm = blockIdx.y, which = blockIdx.z;

    const bf16* A0 = xb + (size_t)(bm * 128) * DM;
    const bf16* B0 = Wt + (size_t)which * DM * DM + (size_t)(bn * 128) * DM;
    const float* bias = (which == 0) ? bq : (which == 1) ? bk : bv;
    bf16* outb = qkv + (size_t)which * (BATCH * SEQL * NH * DH);
    const float oscale = (which == 0) ? QSCALE : 1.0f;

    f32x4 acc[4][4];
    #pragma unroll
    for (int i = 0; i < 4; ++i)
        #pragma unroll
        for (int j = 0; j < 4; ++j) acc[i][j] = (f32x4){0.f, 0.f, 0.f, 0.f};

    const int r0 = t >> 2, c0 = (t & 3) * 8;
    const int f1 = t + 256;
    const int r1 = f1 >> 2, c1 = (f1 & 3) * 8;

    for (int kt = 0; kt < DM / 64; ++kt) {
        const int k0 = kt * 64;
        __syncthreads();
        #pragma unroll
        for (int half = 0; half < 2; ++half) {
            const int kh = k0 + half * 32;
            gl_lds16(A0 + (size_t)r0 * DM + kh + c0, &As[half][t * 8]);
            gl_lds16(A0 + (size_t)r1 * DM + kh + c1, &As[half][f1 * 8]);
            gl_lds16(B0 + (size_t)r0 * DM + kh + c0, &Bs[half][t * 8]);
            gl_lds16(B0 + (size_t)r1 * DM + kh + c1, &Bs[half][f1 * 8]);
        }
        __syncthreads();
        #pragma unroll
        for (int half = 0; half < 2; ++half) {
            bf16x8 af[4], bfr[4];
            #pragma unroll
            for (int i = 0; i < 4; ++i)
                af[i] = *(const bf16x8*)&As[half][(wr * 64 + i * 16 + ml) * 32 + quad * 8];
            #pragma unroll
            for (int j = 0; j < 4; ++j)
                bfr[j] = *(const bf16x8*)&Bs[half][(wc * 64 + j * 16 + ml) * 32 + quad * 8];
            #pragma unroll
            for (int i = 0; i < 4; ++i)
                #pragma unroll
                for (int j = 0; j < 4; ++j)
                    acc[i][j] = __builtin_amdgcn_mfma_f32_16x16x32_bf16(af[i], bfr[j], acc[i][j], 0, 0, 0);
        }
    }

    float bb[4];
    #pragma unroll
    for (int j = 0; j < 4; ++j) bb[j] = bias[bn * 128 + wc * 64 + j * 16 + ml];

    if (which == 2) {
        #pragma unroll
        for (int i = 0; i < 4; ++i) {
            const int row0v = bm * 128 + wr * 64 + i * 16 + quad * 4;
            const int b = row0v >> 11;
            const int s0 = row0v & (SEQL - 1);
            #pragma unroll
            for (int j = 0; j < 4; ++j) {
                const int col = bn * 128 + wc * 64 + j * 16 + ml;
                const int h = col >> 6, d = col & 63;
                bf16 tmp[4];
                #pragma unroll
                for (int rg = 0; rg < 4; ++rg)
                    tmp[rg] = __float2bfloat16(acc[i][j][rg] + bb[j]);
                *(uint2*)&outb[(((size_t)(b * NH + h)) * DH + d) * SEQL + s0] =
                    *(const uint2*)tmp;
            }
        }
    } else {
        #pragma unroll
        for (int i = 0; i < 4; ++i) {
            #pragma unroll
            for (int rg = 0; rg < 4; ++rg) {
                const int row = bm * 128 + wr * 64 + i * 16 + quad * 4 + rg;
                const int b = row >> 11;
                const int s = row & (SEQL - 1);
                #pragma unroll
                for (int j = 0; j < 4; ++j) {
                    const int col = bn * 128 + wc * 64 + j * 16 + ml;
                    const int h = col >> 6, d = col & 63;
                    outb[(((size_t)(b * NH + h)) * SEQL + s) * DH + d] =
                        __float2bfloat16((acc[i][j][rg] + bb[j]) * oscale);
                }
            }
        }
    }
}

// ---------------------------------------------------------------------------
// O-proj GEMM v3: 128x64 tiles, 2 K-steps per barrier. grid (16,32), block 256.
// ---------------------------------------------------------------------------
__global__ __launch_bounds__(256) void oproj_gemm(
    const bf16* __restrict__ zb, const bf16* __restrict__ Bt,
    const float* __restrict__ bo, float* __restrict__ out)
{
    __shared__ __align__(16) bf16 As[2][128 * 32];
    __shared__ __align__(16) bf16 Bs[2][64 * 32];

    const int t = threadIdx.x;
    const int lane = t & 63, w = t >> 6;
    const int ml = lane & 15, quad = lane >> 4;
    const int wr = w >> 1, wc = w & 1;
    const int bn = blockIdx.x, bm = blockIdx.y;

    const bf16* A0 = zb + (size_t)(bm * 128) * DM;
    const bf16* B0 = Bt + (size_t)(bn * 64) * DM;

    f32x4 acc[4][2];
    #pragma unroll
    for (int i = 0; i < 4; ++i)
        #pragma unroll
        for (int j = 0; j < 2; ++j) acc[i][j] = (f32x4){0.f, 0.f, 0.f, 0.f};

    const int r0 = t >> 2, c0 = (t & 3) * 8;
    const int f1 = t + 256;
    const int r1 = f1 >> 2, c1 = (f1 & 3) * 8;

    for (int kt = 0; kt < DM / 64; ++kt) {
        const int k0 = kt * 64;
        __syncthreads();
        #pragma unroll
        for (int half = 0; half < 2; ++half) {
            const int kh = k0 + half * 32;
            gl_lds16(A0 + (size_t)r0 * DM + kh + c0, &As[half][t * 8]);
            gl_lds16(A0 + (size_t)r1 * DM + kh + c1, &As[half][f1 * 8]);
            gl_lds16(B0 + (size_t)r0 * DM + kh + c0, &Bs[half][t * 8]);
        }
        __syncthreads();
        #pragma unroll
        for (int half = 0; half < 2; ++half) {
            bf16x8 af[4], bfr[2];
            #pragma unroll
            for (int i = 0; i < 4; ++i)
                af[i] = *(const bf16x8*)&As[half][(wr * 64 + i * 16 + ml) * 32 + quad * 8];
            #pragma unroll
            for (int j = 0; j < 2; ++j)
                bfr[j] = *(const bf16x8*)&Bs[half][(wc * 32 + j * 16 + ml) * 32 + quad * 8];
            #pragma unroll
            for (int i = 0; i < 4; ++i)
                #pragma unroll
                for (int j = 0; j < 2; ++j)
                    acc[i][j] = __builtin_amdgcn_mfma_f32_16x16x32_bf16(af[i], bfr[j], acc[i][j], 0, 0, 0);
        }
    }

    float bb[2];
    #pragma unroll
    for (int j = 0; j < 2; ++j) bb[j] = bo[bn * 64 + wc * 32 + j * 16 + ml];

    #pragma unroll
    for (int i = 0; i < 4; ++i) {
        #pragma unroll
        for (int rg = 0; rg < 4; ++rg) {
            const int row = bm * 128 + wr * 64 + i * 16 + quad * 4 + rg;
            #pragma unroll
            for (int j = 0; j < 2; ++j) {
                const int col = bn * 64 + wc * 32 + j * 16 + ml;
                out[(size_t)row * DM + col] = acc[i][j][rg] + bb[j];
            }
        }
    }
}

// ---------------------------------------------------------------------------
// MFMA flash attention v8: PAIRED Q-TILES for perfect causal load balance.
// Block = 512 thr (8 waves) handles q-tiles a=blockIdx.y and b=31-a of one
// (batch,head): work = (a+1)+(32-a) = 33 tile-iters for EVERY block.
//  - phase 1 (kt<=a): waves 0-3 -> tile a, waves 4-7 -> tile b (full 64 kv),
//    shared K/V staging (1 gl_lds16 per array per wave).
//  - at kt==a: waves 0-3 finalize+write tile a, reset accumulators, switch
//    their Q frag to tile b's rows.
//  - phase 2 (a<kt<=b): all 8 waves on tile b; wave pair (w,w+4) covers row
//    group (w&3) with kv halves 0/1; partial z/l summed via LDS at the end.
// Per-block wall = (a+1) + (31-2a)/2 = 16.5 uniform iters; 512 blocks, all
// resident (2/CU), 4 waves/SIMD sustained. grid (bh=32, pair=16), block 512.
// ---------------------------------------------------------------------------
__global__ __launch_bounds__(512) void attn_kernel(
    const bf16* __restrict__ qg, const bf16* __restrict__ kg, const bf16* __restrict__ vtg,
    bf16* __restrict__ z)
{
    __shared__ __align__(16) bf16 KsS[64 * 64];   // 8192 B, swizzled [kv][d]
    __shared__ __align__(16) bf16 VtS[64 * 64];   // 8192 B, swizzled [d][kv]
    __shared__ __align__(16) bf16 PsS[8][16 * LDK];  // 18432 B (per-wave P tiles)

    const int t    = threadIdx.x;
    const int lane = t & 63;
    const int w    = t >> 6;          // 0..7
    const int m    = lane & 15;
    const int quad = lane >> 4;
    const int wg   = w & 3;           // row-group within its tile
    const int half = w >> 2;          // kv half in phase 2

    const int bh = blockIdx.x;
    const int b  = bh >> 4;
    const int h  = bh & 15;
    const int qa = blockIdx.y;        // 0..15
    const int qb = 31 - qa;           // 16..31
    const int q0a = qa * 64;
    const int q0b = qb * 64;

    const size_t base   = (size_t)bh * SEQL * DH;  // q/k base ([b,h,s,d])
    const size_t vtbase = (size_t)bh * DH * SEQL;  // v^T base ([b,h,d,s])

    // staging: 8 waves x 64 lanes = 512 slots of 16B per array
    const int s  = t;
    const int rs = s >> 3, cs = (s & 7) ^ (rs & 7);

    // Q fragments: phase-1 rows; waves 0-3 also preload tile b's rows (phase 2)
    bf16x8 aq[2], aqB[2];
    {
        const int myq = (w < 4) ? (q0a + w * 16) : (q0b + wg * 16);
        const bf16* qp = qg + base + (size_t)(myq + m) * DH + quad * 8;
        aq[0] = *(const bf16x8*)(qp);
        aq[1] = *(const bf16x8*)(qp + 32);
        const bf16* qpb = qg + base + (size_t)(q0b + wg * 16 + m) * DH + quad * 8;
        aqB[0] = *(const bf16x8*)(qpb);
        aqB[1] = *(const bf16x8*)(qpb + 32);
    }

    const short ob = (m == 0) ? (short)0x3F80 : (short)0;
    const bf16x8 bones = {ob, ob, ob, ob, ob, ob, ob, ob};

    f32x4 zacc[4];
    #pragma unroll
    for (int nt = 0; nt < 4; ++nt) zacc[nt] = (f32x4){0.f, 0.f, 0.f, 0.f};
    f32x4 lacc = (f32x4){0.f, 0.f, 0.f, 0.f};

    bf16* Psw = PsS[w];

    for (int kt = 0; kt <= qb; ++kt) {
        __syncthreads();
        // ---- stage K and V^T (all 8 waves, 1 instr per array each) ----
        {
            const int kc = kt * 64;
            gl_lds16(kg + base + (size_t)(kc + rs) * DH + cs * 8, &KsS[s * 8]);
            gl_lds16(vtg + vtbase + (size_t)rs * SEQL + kc + cs * 8, &VtS[s * 8]);
        }
        __syncthreads();

        if (kt <= qa) {
            // ---------- phase 1: full-width, waves 0-3 tile a, 4-7 tile b ----
            f32x4 sc[4];
            #pragma unroll
            for (int nt = 0; nt < 4; ++nt) sc[nt] = (f32x4){0.f, 0.f, 0.f, 0.f};
            __builtin_amdgcn_s_setprio(1);
            #pragma unroll
            for (int ks = 0; ks < 2; ++ks) {
                #pragma unroll
                for (int nt = 0; nt < 4; ++nt) {
                    const int row = nt * 16 + m;
                    const int pc  = ((ks << 2) + quad) ^ (m & 7);
                    const bf16x8 bk = *(const bf16x8*)(&KsS[row * 64 + pc * 8]);
                    sc[nt] = __builtin_amdgcn_mfma_f32_16x16x32_bf16(aq[ks], bk, sc[nt], 0, 0, 0);
                }
            }
            __builtin_amdgcn_s_setprio(0);
            if (kt == qa && w < 4) {   // tile a's diagonal (b's diag is at qb)
                #pragma unroll
                for (int nt = 0; nt < 4; ++nt) {
                    const int col = nt * 16 + m;
                    #pragma unroll
                    for (int rg = 0; rg < 4; ++rg) {
                        const int row = wg * 16 + quad * 4 + rg;
                        if (col > row) sc[nt][rg] = -1e30f;
                    }
                }
            }

            // p = 2^s (no max; offset cancels in z = sum(pv)/sum(p))
            #pragma unroll
            for (int nt = 0; nt < 4; ++nt)
                #pragma unroll
                for (int rg = 0; rg < 4; ++rg)
                    Psw[(quad * 4 + rg) * LDK + nt * 16 + m] =
                        __float2bfloat16(__builtin_exp2f(sc[nt][rg]));

            __builtin_amdgcn_s_setprio(1);
            #pragma unroll
            for (int ks = 0; ks < 2; ++ks) {
                const bf16x8 ap = *(const bf16x8*)(&Psw[m * LDK + ks * 32 + quad * 8]);
                lacc = __builtin_amdgcn_mfma_f32_16x16x32_bf16(ap, bones, lacc, 0, 0, 0);
                #pragma unroll
                for (int nt = 0; nt < 4; ++nt) {
                    const int row = nt * 16 + m;
                    const int pc  = ((ks << 2) + quad) ^ (m & 7);
                    const bf16x8 bv = *(const bf16x8*)(&VtS[row * 64 + pc * 8]);
                    zacc[nt] = __builtin_amdgcn_mfma_f32_16x16x32_bf16(ap, bv, zacc[nt], 0, 0, 0);
                }
            }
            __builtin_amdgcn_s_setprio(0);

            if (kt == qa && w < 4) {
                // ---- finalize + write tile a, then switch to tile b ----
                float invl[4];
                #pragma unroll
                for (int rg = 0; rg < 4; ++rg)
                    invl[rg] = 1.f / __shfl(lacc[rg], quad * 16);
                #pragma unroll
                for (int nt = 0; nt < 4; ++nt) {
                    const int d = nt * 16 + m;
                    #pragma unroll
                    for (int rg = 0; rg < 4; ++rg) {
                        const int qrow = q0a + wg * 16 + quad * 4 + rg;
                        z[(((size_t)b * SEQL + qrow) * NH + h) * DH + d] =
                            __float2bfloat16(zacc[nt][rg] * invl[rg]);
                    }
                }
                #pragma unroll
                for (int nt = 0; nt < 4; ++nt) zacc[nt] = (f32x4){0.f, 0.f, 0.f, 0.f};
                lacc = (f32x4){0.f, 0.f, 0.f, 0.f};
                aq[0] = aqB[0]; aq[1] = aqB[1];
            }
        } else {
            // ---------- phase 2: all waves on tile b, kv halves split --------
            f32x4 sc[2];
            sc[0] = (f32x4){0.f, 0.f, 0.f, 0.f};
            sc[1] = (f32x4){0.f, 0.f, 0.f, 0.f};
            __builtin_amdgcn_s_setprio(1);
            #pragma unroll
            for (int ks = 0; ks < 2; ++ks) {
                #pragma unroll
                for (int nt = 0; nt < 2; ++nt) {
                    const int row = half * 32 + nt * 16 + m;   // kv row
                    const int pc  = ((ks << 2) + quad) ^ (m & 7);
                    const bf16x8 bk = *(const bf16x8*)(&KsS[row * 64 + pc * 8]);
                    sc[nt] = __builtin_amdgcn_mfma_f32_16x16x32_bf16(aq[ks], bk, sc[nt], 0, 0, 0);
                }
            }
            __builtin_amdgcn_s_setprio(0);
            if (kt == qb) {   // tile b's diagonal
                #pragma unroll
                for (int nt = 0; nt < 2; ++nt) {
                    const int col = half * 32 + nt * 16 + m;
                    #pragma unroll
                    for (int rg = 0; rg < 4; ++rg) {
                        const int row = wg * 16 + quad * 4 + rg;
                        if (col > row) sc[nt][rg] = -1e30f;
                    }
                }
            }

            #pragma unroll
            for (int nt = 0; nt < 2; ++nt)
                #pragma unroll
                for (int rg = 0; rg < 4; ++rg)
                    Psw[(quad * 4 + rg) * LDK + nt * 16 + m] =
                        __float2bfloat16(__builtin_exp2f(sc[nt][rg]));

            __builtin_amdgcn_s_setprio(1);
            {
                const bf16x8 ap = *(const bf16x8*)(&Psw[m * LDK + quad * 8]);
                lacc = __builtin_amdgcn_mfma_f32_16x16x32_bf16(ap, bones, lacc, 0, 0, 0);
                #pragma unroll
                for (int nt = 0; nt < 4; ++nt) {
                    const int row = nt * 16 + m;
                    const int pc  = ((half << 2) + quad) ^ (m & 7);
                    const bf16x8 bv = *(const bf16x8*)(&VtS[row * 64 + pc * 8]);
                    zacc[nt] = __builtin_amdgcn_mfma_f32_16x16x32_bf16(ap, bv, zacc[nt], 0, 0, 0);
                }
            }
            __builtin_amdgcn_s_setprio(0);
        }
    }

    // ---- combine tile b partials across wave pairs (w, w+4) via LDS ----
    __syncthreads();   // all compute done; K/V LDS reusable as f32 scratch
    if (w < 4) {
        float* zs = (w < 2) ? ((float*)KsS) + (size_t)w * 1024
                            : ((float*)VtS) + (size_t)(w - 2) * 1024;
        #pragma unroll
        for (int nt = 0; nt < 4; ++nt)
            #pragma unroll
            for (int rg = 0; rg < 4; ++rg)
                zs[lane * 16 + nt * 4 + rg] = zacc[nt][rg];
        float* ls = ((float*)PsS) + w * 256;
        #pragma unroll
        for (int rg = 0; rg < 4; ++rg) ls[lane * 4 + rg] = lacc[rg];
    }
    __syncthreads();
    if (w >= 4) {
        const int ww = w - 4;
        const float* zs = (ww < 2) ? ((const float*)KsS) + (size_t)ww * 1024
                                   : ((const float*)VtS) + (size_t)(ww - 2) * 1024;
        const float* ls = ((const float*)PsS) + ww * 256;
        #pragma unroll
        for (int nt = 0; nt < 4; ++nt)
            #pragma unroll
            for (int rg = 0; rg < 4; ++rg)
                zacc[nt][rg] += zs[lane * 16 + nt * 4 + rg];
        #pragma unroll
        for (int rg = 0; rg < 4; ++rg) lacc[rg] += ls[lane * 4 + rg];

        float invl[4];
        #pragma unroll
        for (int rg = 0; rg < 4; ++rg)
            invl[rg] = 1.f / __shfl(lacc[rg], quad * 16);
        #pragma unroll
        for (int nt = 0; nt < 4; ++nt) {
            const int d = nt * 16 + m;
            #pragma unroll
            for (int rg = 0; rg < 4; ++rg) {
                const int qrow = q0b + wg * 16 + quad * 4 + rg;
                z[(((size_t)b * SEQL + qrow) * NH + h) * DH + d] =
                    __float2bfloat16(zacc[nt][rg] * invl[rg]);
            }
        }
    }
}

// ---------------------------------------------------------------------------
extern "C" void kernel_launch(void* const* d_in, const int* in_sizes, int n_in,
                              void* d_out, int out_size, void* d_ws, size_t ws_size,
                              hipStream_t stream)
{
    const float* x  = (const float*)d_in[0];
    const float* Wq = (const float*)d_in[1];
    const float* Wk = (const float*)d_in[2];
    const float* Wv = (const float*)d_in[3];
    const float* Wo = (const float*)d_in[4];
    const float* bq = (const float*)d_in[5];
    const float* bk = (const float*)d_in[6];
    const float* bv = (const float*)d_in[7];
    const float* bo = (const float*)d_in[8];
    float* out = (float*)d_out;

    const size_t TOK = (size_t)BATCH * SEQL;             // 4096
    const size_t QKV = TOK * DM;                         // 4M elems
    bf16* xb  = (bf16*)d_ws;                             // 4M
    bf16* Wt  = xb + QKV;                                // 4 x 1M
    bf16* qkv = Wt + 4 * (size_t)DM * DM;                // 3 x 4M
    bf16* zb  = qkv + 3 * QKV;                           // 4M   (48 MB total)

    prep_kernel<<<dim3(16, 16, 5), 256, 0, stream>>>(x, Wq, Wk, Wv, Wo, Wt, xb);
    qkv_gemm<<<dim3(8, 32, 3), 256, 0, stream>>>(xb, Wt, bq, bk, bv, qkv);
    attn_kernel<<<dim3(BATCH * NH, 16), 512, 0, stream>>>(
        qkv, qkv + QKV, qkv + 2 * QKV, zb);
    oproj_gemm<<<dim3(16, 32), 256, 0, stream>>>(zb, Wt + 3 * (size_t)DM * DM, bo, out);
}

// Round 3
// 183.338 us; speedup vs baseline: 1.0267x; 1.0078x over previous
//
#include <hip/hip_runtime.h>
#include <hip/hip_bf16.h>

#define BATCH 2
#define SEQL 2048
#define NH 16
#define DH 64
#define DM 1024
// Q pre-scale folded into qkv_gemm epilogue: 1/sqrt(64) * log2(e)
#define QSCALE 0.1803368801111244f

typedef __hip_bfloat16 bf16;
typedef __attribute__((ext_vector_type(8)))  short bf16x8;
typedef __attribute__((ext_vector_type(4)))  float f32x4;
typedef __attribute__((ext_vector_type(16))) float f32x16;

__device__ __forceinline__ void gl_lds16(const void* g, void* l) {
    __builtin_amdgcn_global_load_lds(
        (const __attribute__((address_space(1))) unsigned int*)g,
        (__attribute__((address_space(3))) unsigned int*)l, 16, 0, 0);
}

__device__ __forceinline__ unsigned int pkbf(float a, float b) {
    union { bf16 h[2]; unsigned int u; } x;
    x.h[0] = __float2bfloat16(a); x.h[1] = __float2bfloat16(b);
    return x.u;
}

// ---------------------------------------------------------------------------
// Prep (fused): z<4 -> weight transpose to bf16 Bt[n][k]; z==4 -> x fp32->bf16
// (grid-stride). grid (16,16,5), block 256.
// ---------------------------------------------------------------------------
__global__ __launch_bounds__(256) void prep_kernel(
    const float* __restrict__ x,
    const float* __restrict__ Wq, const float* __restrict__ Wk,
    const float* __restrict__ Wv, const float* __restrict__ Wo,
    bf16* __restrict__ Wt, bf16* __restrict__ xb)
{
    const int zi = blockIdx.z;
    if (zi == 4) {
        const int bid = blockIdx.y * 16 + blockIdx.x;
        const size_t base = ((size_t)bid * 256 + threadIdx.x) * 4;
        #pragma unroll
        for (int it = 0; it < 16; ++it) {
            const size_t i = base + (size_t)it * 262144;
            const float4 v = *(const float4*)(x + i);
            bf16 o[4];
            o[0] = __float2bfloat16(v.x); o[1] = __float2bfloat16(v.y);
            o[2] = __float2bfloat16(v.z); o[3] = __float2bfloat16(v.w);
            *(uint2*)(xb + i) = *(const uint2*)o;
        }
        return;
    }

    __shared__ float ts[64][65];
    const float* src = (zi == 0) ? Wq : (zi == 1) ? Wk : (zi == 2) ? Wv : Wo;
    bf16* dst = Wt + (size_t)zi * DM * DM;
    const int row0 = blockIdx.y * 64;
    const int col0 = blockIdx.x * 64;
    const int tx = threadIdx.x & 63;
    const int ty = threadIdx.x >> 6;

    if (zi < 3) {
        const int h = col0 >> 6;
        #pragma unroll
        for (int i = 0; i < 16; ++i) {
            const int r = ty + 4 * i;
            ts[r][tx] = src[h * (DM * DH) + (row0 + r) * DH + tx];
        }
    } else {
        #pragma unroll
        for (int i = 0; i < 16; ++i) {
            const int r = ty + 4 * i;
            ts[r][tx] = src[(size_t)(row0 + r) * DM + col0 + tx];
        }
    }
    __syncthreads();
    #pragma unroll
    for (int i = 0; i < 16; ++i) {
        const int rr = ty + 4 * i;
        dst[(size_t)(col0 + rr) * DM + row0 + tx] = __float2bfloat16(ts[tx][rr]);
    }
}

// ---------------------------------------------------------------------------
// QKV GEMM v3 (round-10 config): 2 K-steps per barrier, round-6 epilogue.
// grid (8, 32, 3), block 256.
// ---------------------------------------------------------------------------
__global__ __launch_bounds__(256) void qkv_gemm(
    const bf16* __restrict__ xb, const bf16* __restrict__ Wt,
    const float* __restrict__ bq, const float* __restrict__ bk, const float* __restrict__ bv,
    bf16* __restrict__ qkv)
{
    __shared__ __align__(16) bf16 As[2][128 * 32];
    __shared__ __align__(16) bf16 Bs[2][128 * 32];

    const int t = threadIdx.x;
    const int lane = t & 63, w = t >> 6;
    const int ml = lane & 15, quad = lane >> 4;
    const int wr = w >> 1, wc = w & 1;
    const int bn = blockIdx.x, bm = blockIdx.y, which = blockIdx.z;

    const bf16* A0 = xb + (size_t)(bm * 128) * DM;
    const bf16* B0 = Wt + (size_t)which * DM * DM + (size_t)(bn * 128) * DM;
    const float* bias = (which == 0) ? bq : (which == 1) ? bk : bv;
    bf16* outb = qkv + (size_t)which * (BATCH * SEQL * NH * DH);
    const float oscale = (which == 0) ? QSCALE : 1.0f;

    f32x4 acc[4][4];
    #pragma unroll
    for (int i = 0; i < 4; ++i)
        #pragma unroll
        for (int j = 0; j < 4; ++j) acc[i][j] = (f32x4){0.f, 0.f, 0.f, 0.f};

    const int r0 = t >> 2, c0 = (t & 3) * 8;
    const int f1 = t + 256;
    const int r1 = f1 >> 2, c1 = (f1 & 3) * 8;

    for (int kt = 0; kt < DM / 64; ++kt) {
        const int k0 = kt * 64;
        __syncthreads();
        #pragma unroll
        for (int half = 0; half < 2; ++half) {
            const int kh = k0 + half * 32;
            gl_lds16(A0 + (size_t)r0 * DM + kh + c0, &As[half][t * 8]);
            gl_lds16(A0 + (size_t)r1 * DM + kh + c1, &As[half][f1 * 8]);
            gl_lds16(B0 + (size_t)r0 * DM + kh + c0, &Bs[half][t * 8]);
            gl_lds16(B0 + (size_t)r1 * DM + kh + c1, &Bs[half][f1 * 8]);
        }
        __syncthreads();
        #pragma unroll
        for (int half = 0; half < 2; ++half) {
            bf16x8 af[4], bfr[4];
            #pragma unroll
            for (int i = 0; i < 4; ++i)
                af[i] = *(const bf16x8*)&As[half][(wr * 64 + i * 16 + ml) * 32 + quad * 8];
            #pragma unroll
            for (int j = 0; j < 4; ++j)
                bfr[j] = *(const bf16x8*)&Bs[half][(wc * 64 + j * 16 + ml) * 32 + quad * 8];
            #pragma unroll
            for (int i = 0; i < 4; ++i)
                #pragma unroll
                for (int j = 0; j < 4; ++j)
                    acc[i][j] = __builtin_amdgcn_mfma_f32_16x16x32_bf16(af[i], bfr[j], acc[i][j], 0, 0, 0);
        }
    }

    float bb[4];
    #pragma unroll
    for (int j = 0; j < 4; ++j) bb[j] = bias[bn * 128 + wc * 64 + j * 16 + ml];

    if (which == 2) {
        #pragma unroll
        for (int i = 0; i < 4; ++i) {
            const int row0v = bm * 128 + wr * 64 + i * 16 + quad * 4;
            const int b = row0v >> 11;
            const int s0 = row0v & (SEQL - 1);
            #pragma unroll
            for (int j = 0; j < 4; ++j) {
                const int col = bn * 128 + wc * 64 + j * 16 + ml;
                const int h = col >> 6, d = col & 63;
                bf16 tmp[4];
                #pragma unroll
                for (int rg = 0; rg < 4; ++rg)
                    tmp[rg] = __float2bfloat16(acc[i][j][rg] + bb[j]);
                *(uint2*)&outb[(((size_t)(b * NH + h)) * DH + d) * SEQL + s0] =
                    *(const uint2*)tmp;
            }
        }
    } else {
        #pragma unroll
        for (int i = 0; i < 4; ++i) {
            #pragma unroll
            for (int rg = 0; rg < 4; ++rg) {
                const int row = bm * 128 + wr * 64 + i * 16 + quad * 4 + rg;
                const int b = row >> 11;
                const int s = row & (SEQL - 1);
                #pragma unroll
                for (int j = 0; j < 4; ++j) {
                    const int col = bn * 128 + wc * 64 + j * 16 + ml;
                    const int h = col >> 6, d = col & 63;
                    outb[(((size_t)(b * NH + h)) * SEQL + s) * DH + d] =
                        __float2bfloat16((acc[i][j][rg] + bb[j]) * oscale);
                }
            }
        }
    }
}

// ---------------------------------------------------------------------------
// O-proj GEMM v3: 128x64 tiles, 2 K-steps per barrier. grid (16,32), block 256.
// ---------------------------------------------------------------------------
__global__ __launch_bounds__(256) void oproj_gemm(
    const bf16* __restrict__ zb, const bf16* __restrict__ Bt,
    const float* __restrict__ bo, float* __restrict__ out)
{
    __shared__ __align__(16) bf16 As[2][128 * 32];
    __shared__ __align__(16) bf16 Bs[2][64 * 32];

    const int t = threadIdx.x;
    const int lane = t & 63, w = t >> 6;
    const int ml = lane & 15, quad = lane >> 4;
    const int wr = w >> 1, wc = w & 1;
    const int bn = blockIdx.x, bm = blockIdx.y;

    const bf16* A0 = zb + (size_t)(bm * 128) * DM;
    const bf16* B0 = Bt + (size_t)(bn * 64) * DM;

    f32x4 acc[4][2];
    #pragma unroll
    for (int i = 0; i < 4; ++i)
        #pragma unroll
        for (int j = 0; j < 2; ++j) acc[i][j] = (f32x4){0.f, 0.f, 0.f, 0.f};

    const int r0 = t >> 2, c0 = (t & 3) * 8;
    const int f1 = t + 256;
    const int r1 = f1 >> 2, c1 = (f1 & 3) * 8;

    for (int kt = 0; kt < DM / 64; ++kt) {
        const int k0 = kt * 64;
        __syncthreads();
        #pragma unroll
        for (int half = 0; half < 2; ++half) {
            const int kh = k0 + half * 32;
            gl_lds16(A0 + (size_t)r0 * DM + kh + c0, &As[half][t * 8]);
            gl_lds16(A0 + (size_t)r1 * DM + kh + c1, &As[half][f1 * 8]);
            gl_lds16(B0 + (size_t)r0 * DM + kh + c0, &Bs[half][t * 8]);
        }
        __syncthreads();
        #pragma unroll
        for (int half = 0; half < 2; ++half) {
            bf16x8 af[4], bfr[2];
            #pragma unroll
            for (int i = 0; i < 4; ++i)
                af[i] = *(const bf16x8*)&As[half][(wr * 64 + i * 16 + ml) * 32 + quad * 8];
            #pragma unroll
            for (int j = 0; j < 2; ++j)
                bfr[j] = *(const bf16x8*)&Bs[half][(wc * 32 + j * 16 + ml) * 32 + quad * 8];
            #pragma unroll
            for (int i = 0; i < 4; ++i)
                #pragma unroll
                for (int j = 0; j < 2; ++j)
                    acc[i][j] = __builtin_amdgcn_mfma_f32_16x16x32_bf16(af[i], bfr[j], acc[i][j], 0, 0, 0);
        }
    }

    float bb[2];
    #pragma unroll
    for (int j = 0; j < 2; ++j) bb[j] = bo[bn * 64 + wc * 32 + j * 16 + ml];

    #pragma unroll
    for (int i = 0; i < 4; ++i) {
        #pragma unroll
        for (int rg = 0; rg < 4; ++rg) {
            const int row = bm * 128 + wr * 64 + i * 16 + quad * 4 + rg;
            #pragma unroll
            for (int j = 0; j < 2; ++j) {
                const int col = bn * 64 + wc * 32 + j * 16 + ml;
                out[(size_t)row * DM + col] = acc[i][j][rg] + bb[j];
            }
        }
    }
}

// ---------------------------------------------------------------------------
// MFMA flash attention v9: 32x32x16 MFMA, swapped QK^T (S^T = K·Q^T), fully
// IN-REGISTER P (no P LDS round-trip). Per 64-row q-tile: 4 waves, wave w =
// (kvg = w>>1, qg = w&1) owns S^T subtile [kvg*32 kv][qg*32 q]. Each lane
// holds P^T[16 kv][one q=lane&31]; softmax is lane-local (exp2 + f32 l-sum).
// P -> PV B-operand needs only a lane<->lane^32 half-swap of packed bf16
// words (4 shfl_xor). PV: Z^T[d][q] += V^T·P^T, kvg partials combined once
// via LDS in the epilogue. DS traffic/wave-iter: 8 ds_read_b128 + 4 bpermute
// (was ~18 b128 + 16 b16-writes + 2 b128 P reloads). K/V double-buffered,
// prefetch issued before compute (round-1 pipeline). LDS 32KB, no PsS.
// grid = (bh=32, qt=32 reversed), block 256.
// ---------------------------------------------------------------------------
__global__ __launch_bounds__(256) void attn_kernel(
    const bf16* __restrict__ qg, const bf16* __restrict__ kg, const bf16* __restrict__ vtg,
    bf16* __restrict__ z)
{
    __shared__ __align__(16) bf16 KsS[2][64 * 64];   // 2 x 8 KB, swizzled [kv][d]
    __shared__ __align__(16) bf16 VtS[2][64 * 64];   // 2 x 8 KB, swizzled [d][kv]

    const int t    = threadIdx.x;
    const int lane = t & 63;
    const int w    = t >> 6;          // 0..3
    const int q5   = lane & 31;       // q within 32-col group (also V^T d row)
    const int hl   = lane >> 5;       // lane half
    const int qgr  = w & 1;           // q group (0..1)
    const int kvg  = w >> 1;          // kv group (0..1)

    const int bh = blockIdx.x;
    const int b  = bh >> 4;
    const int h  = bh & 15;
    const int qt = (gridDim.y - 1) - blockIdx.y;
    const int q0 = qt * 64;

    const size_t base   = (size_t)bh * SEQL * DH;  // q/k base ([b,h,s,d])
    const size_t vtbase = (size_t)bh * DH * SEQL;  // v^T base ([b,h,d,s])

    // staging slots: 256 thr x 2 slots x 16B per array (512 slots = 8KB)
    const int s0 = t, s1 = t + 256;
    const int r0s = s0 >> 3, c0s = (s0 & 7) ^ (r0s & 7);
    const int r1s = s1 >> 3, c1s = (s1 & 7) ^ (r1s & 7);

    // Q as persistent B-operand frags: Q[q0+qgr*32+q5][c*16 + hl*8 + j], c=0..3
    bf16x8 aq[4];
    {
        const bf16* qp = qg + base + (size_t)(q0 + qgr * 32 + q5) * DH;
        #pragma unroll
        for (int c = 0; c < 4; ++c)
            aq[c] = *(const bf16x8*)(qp + c * 16 + hl * 8);
    }

    f32x16 zacc[2];
    #pragma unroll
    for (int dg = 0; dg < 2; ++dg)
        #pragma unroll
        for (int r = 0; r < 16; ++r) zacc[dg][r] = 0.f;
    float lacc = 0.f;

    // ---- prologue: stage tile 0 into buffer 0 ----
    gl_lds16(kg + base + (size_t)r0s * DH + c0s * 8, &KsS[0][s0 * 8]);
    gl_lds16(kg + base + (size_t)r1s * DH + c1s * 8, &KsS[0][s1 * 8]);
    gl_lds16(vtg + vtbase + (size_t)r0s * SEQL + c0s * 8, &VtS[0][s0 * 8]);
    gl_lds16(vtg + vtbase + (size_t)r1s * SEQL + c1s * 8, &VtS[0][s1 * 8]);

    for (int kt = 0; kt <= qt; ++kt) {
        const int cur = kt & 1;
        __syncthreads();   // drains own gl_lds (vmcnt0) + publishes tile kt

        if (kt < qt) {     // prefetch tile kt+1 into other buffer
            const int kc = (kt + 1) * 64;
            bf16* Kd = &KsS[cur ^ 1][0];
            bf16* Vd = &VtS[cur ^ 1][0];
            gl_lds16(kg + base + (size_t)(kc + r0s) * DH + c0s * 8, Kd + s0 * 8);
            gl_lds16(kg + base + (size_t)(kc + r1s) * DH + c1s * 8, Kd + s1 * 8);
            gl_lds16(vtg + vtbase + (size_t)r0s * SEQL + kc + c0s * 8, Vd + s0 * 8);
            gl_lds16(vtg + vtbase + (size_t)r1s * SEQL + kc + c1s * 8, Vd + s1 * 8);
        }

        // wave (kvg=1,qgr=0) at the diagonal tile is fully masked -> skip
        if (kt == qt && kvg == 1 && qgr == 0) continue;

        const bf16* Ks = &KsS[cur][0];
        const bf16* Vt = &VtS[cur][0];

        // ---- S^T = K · Q^T : one 32x32 tile per wave, 4 k-steps over d ----
        f32x16 sc;
        #pragma unroll
        for (int r = 0; r < 16; ++r) sc[r] = 0.f;
        {
            const int row = kvg * 32 + q5;       // K row (kv)
            const int rx  = row & 7;
            __builtin_amdgcn_s_setprio(1);
            #pragma unroll
            for (int s = 0; s < 4; ++s) {
                const int cc = (s * 2 + hl) ^ rx;
                const bf16x8 ak = *(const bf16x8*)(&Ks[row * 64 + cc * 8]);
                sc = __builtin_amdgcn_mfma_f32_32x32x16_bf16(ak, aq[s], sc, 0, 0, 0);
            }
            __builtin_amdgcn_s_setprio(0);
        }

        // ---- causal mask on diagonal subtiles (kvg == qgr only) ----
        if (kt == qt && kvg == qgr) {
            #pragma unroll
            for (int r = 0; r < 16; ++r) {
                const int kvloc = (r & 3) + 8 * (r >> 2) + 4 * hl;
                sc[r] = (kvloc > q5) ? -1e30f : sc[r];
            }
        }

        // ---- p = 2^s (lane-local), l-sum, pack to bf16 words ----
        unsigned int wpk[8];
        #pragma unroll
        for (int g = 0; g < 4; ++g) {
            const float p0 = __builtin_exp2f(sc[4 * g + 0]);
            const float p1 = __builtin_exp2f(sc[4 * g + 1]);
            const float p2 = __builtin_exp2f(sc[4 * g + 2]);
            const float p3 = __builtin_exp2f(sc[4 * g + 3]);
            lacc += (p0 + p1) + (p2 + p3);
            wpk[2 * g + 0] = pkbf(p0, p1);
            wpk[2 * g + 1] = pkbf(p2, p3);
        }

        // ---- assemble PV B-frags: lane<->lane^32 half-swap (4 shfl_xor) ----
        bf16x8 pf[2];
        #pragma unroll
        for (int ks = 0; ks < 2; ++ks) {
            const unsigned int S0 = hl ? wpk[4 * ks + 0] : wpk[4 * ks + 2];
            const unsigned int S1 = hl ? wpk[4 * ks + 1] : wpk[4 * ks + 3];
            const unsigned int R0 = __shfl_xor((int)S0, 32);
            const unsigned int R1 = __shfl_xor((int)S1, 32);
            union { unsigned int u[4]; bf16x8 v; } f;
            f.u[0] = hl ? R0 : wpk[4 * ks + 0];
            f.u[1] = hl ? R1 : wpk[4 * ks + 1];
            f.u[2] = hl ? wpk[4 * ks + 2] : R0;
            f.u[3] = hl ? wpk[4 * ks + 3] : R1;
            pf[ks] = f.v;
        }

        // ---- Z^T[d][q] += V^T · P^T  (2 d-groups x 2 kv-steps) ----
        __builtin_amdgcn_s_setprio(1);
        #pragma unroll
        for (int dg = 0; dg < 2; ++dg) {
            const int row = dg * 32 + q5;        // V^T row (d)
            const int rx  = row & 7;
            #pragma unroll
            for (int ks = 0; ks < 2; ++ks) {
                const int cc = (kvg * 4 + ks * 2 + hl) ^ rx;
                const bf16x8 av = *(const bf16x8*)(&Vt[row * 64 + cc * 8]);
                zacc[dg] = __builtin_amdgcn_mfma_f32_32x32x16_bf16(av, pf[ks], zacc[dg], 0, 0, 0);
            }
        }
        __builtin_amdgcn_s_setprio(0);
    }

    // ---- epilogue: combine kvg partials via LDS, normalize, write ----
    __syncthreads();   // all compute done; K/V LDS reusable as f32 scratch
    if (kvg == 1) {
        float* sp = (qgr == 0) ? (float*)KsS : (float*)VtS;
        #pragma unroll
        for (int dg = 0; dg < 2; ++dg)
            #pragma unroll
            for (int r = 0; r < 16; ++r)
                sp[(dg * 16 + r) * 64 + lane] = zacc[dg][r];
        sp[2048 + lane] = lacc;
    }
    __syncthreads();
    if (kvg == 0) {
        const float* sp = (qgr == 0) ? (const float*)KsS : (const float*)VtS;
        #pragma unroll
        for (int dg = 0; dg < 2; ++dg)
            #pragma unroll
            for (int r = 0; r < 16; ++r)
                zacc[dg][r] += sp[(dg * 16 + r) * 64 + lane];
        lacc += sp[2048 + lane];
        lacc += __shfl_xor(lacc, 32);
        const float invl = 1.f / lacc;

        const int qrow = q0 + qgr * 32 + q5;
        bf16* zp = z + (((size_t)b * SEQL + qrow) * NH + h) * DH;
        #pragma unroll
        for (int dg = 0; dg < 2; ++dg) {
            #pragma unroll
            for (int g2 = 0; g2 < 4; ++g2) {
                bf16 tmp[4];
                #pragma unroll
                for (int j = 0; j < 4; ++j)
                    tmp[j] = __float2bfloat16(zacc[dg][4 * g2 + j] * invl);
                *(uint2*)(zp + dg * 32 + 8 * g2 + 4 * hl) = *(const uint2*)tmp;
            }
        }
    }
}

// ---------------------------------------------------------------------------
extern "C" void kernel_launch(void* const* d_in, const int* in_sizes, int n_in,
                              void* d_out, int out_size, void* d_ws, size_t ws_size,
                              hipStream_t stream)
{
    const float* x  = (const float*)d_in[0];
    const float* Wq = (const float*)d_in[1];
    const float* Wk = (const float*)d_in[2];
    const float* Wv = (const float*)d_in[3];
    const float* Wo = (const float*)d_in[4];
    const float* bq = (const float*)d_in[5];
    const float* bk = (const float*)d_in[6];
    const float* bv = (const float*)d_in[7];
    const float* bo = (const float*)d_in[8];
    float* out = (float*)d_out;

    const size_t TOK = (size_t)BATCH * SEQL;             // 4096
    const size_t QKV = TOK * DM;                         // 4M elems
    bf16* xb  = (bf16*)d_ws;                             // 4M
    bf16* Wt  = xb + QKV;                                // 4 x 1M
    bf16* qkv = Wt + 4 * (size_t)DM * DM;                // 3 x 4M
    bf16* zb  = qkv + 3 * QKV;                           // 4M   (48 MB total)

    prep_kernel<<<dim3(16, 16, 5), 256, 0, stream>>>(x, Wq, Wk, Wv, Wo, Wt, xb);
    qkv_gemm<<<dim3(8, 32, 3), 256, 0, stream>>>(xb, Wt, bq, bk, bv, qkv);
    attn_kernel<<<dim3(BATCH * NH, SEQL / 64), 256, 0, stream>>>(
        qkv, qkv + QKV, qkv + 2 * QKV, zb);
    oproj_gemm<<<dim3(16, 32), 256, 0, stream>>>(zb, Wt + 3 * (size_t)DM * DM, bo, out);
}